// Round 3
// baseline (7487.115 us; speedup 1.0000x reference)
//
#include <hip/hip_runtime.h>

// RGCN 2-layer forward for MI355X (gfx950).
// N=50000, D=128, R=16, E=1600000 (from in_sizes at runtime).
//
// Per layer:
//   msg_sum[r,d,:] += x[src,:]  for each edge (src,dst,r);  cnt[r,d] += 1
//   out[n,:] = relu( bias + x[n,:]@root + sum_r (msg_sum[r,n,:]/max(cnt,1)) @ W_r )
//
// Relations processed in chunks of C (adaptive to ws_size; C | 16, C<=4) so the
// msg buffer is C*N*D floats instead of R*N*D (Round-0 assumed 438 MB of ws and
// faulted). Chunk results accumulate into the output across GEMM passes.
//
// ws layout: h (N*D f32) | msg (C*N*D f32) | cnt (C*N f32)

#define ND 128
#define NR 16

// ---------------------------------------------------------------- scatter ---
// 32 threads per edge; each thread handles one float4 (4 atomicAdds).
// Only edges with rel in [r0, r1) contribute to this chunk.
__global__ __launch_bounds__(256) void scatter_kernel(
    const float* __restrict__ x,
    const int* __restrict__ src,
    const int* __restrict__ dst,
    const int* __restrict__ rel,
    float* __restrict__ msg,   // (r1-r0) x N x ND
    float* __restrict__ cnt,   // (r1-r0) x N
    int E, int N, int r0, int r1)
{
    int t = blockIdx.x * 256 + threadIdx.x;
    int e = t >> 5;
    int lane = t & 31;
    if (e >= E) return;
    int r = rel[e];
    if (r < r0 || r >= r1) return;
    int s = src[e];
    int d = dst[e];
    int rl = r - r0;
    float4 v = ((const float4*)(x + (size_t)s * ND))[lane];
    float* mp = msg + ((size_t)rl * N + d) * ND + lane * 4;
    atomicAdd(mp + 0, v.x);
    atomicAdd(mp + 1, v.y);
    atomicAdd(mp + 2, v.z);
    atomicAdd(mp + 3, v.w);
    if (lane == 0) atomicAdd(cnt + (size_t)rl * N + d, 1.0f);
}

// ------------------------------------------------------------------- gemm ---
// One pass: out[n,:] (+)= [A0[n,:]@root if include_root] + sum_{s<nseg} (msg[s,n,:]*inv_cnt)@W_s
// finalize: add bias, apply relu. Non-first passes accumulate onto existing out.
// Block: 256 threads, tile of 64 nodes x 128 cols.
// Thread (ng = tid>>5 in 0..7, c4 = tid&31): 8 nodes (ng + 8j), cols 4*c4..4*c4+3.
__global__ __launch_bounds__(256) void gemm_kernel(
    const float* __restrict__ A0,    // N x 128 input rows (x or h)
    const float* __restrict__ msg,   // nseg x N x 128
    const float* __restrict__ cnt,   // nseg x N
    const float* __restrict__ Wseg,  // nseg x 128 x 128 (host offsets into W by r0)
    const float* __restrict__ root,  // 128 x 128
    const float* __restrict__ bias,  // 128
    float* __restrict__ out,         // N x 128
    int N, int nseg, int include_root, int finalize)
{
    __shared__ float lds[64 * 132];   // 64 rows, stride 132 floats (pad 4)
    const int tid = threadIdx.x;
    const int n0 = blockIdx.x * 64;
    const int c4 = tid & 31;
    const int ng = tid >> 5;

    float acc[8][4];
    if (include_root) {
#pragma unroll
        for (int j = 0; j < 8; ++j)
#pragma unroll
            for (int q = 0; q < 4; ++q) acc[j][q] = 0.f;
    } else {
        // accumulate onto the partial result from previous chunk passes
#pragma unroll
        for (int j = 0; j < 8; ++j) {
            int gn = n0 + ng + j * 8;
            float4 o = make_float4(0.f, 0.f, 0.f, 0.f);
            if (gn < N) o = ((const float4*)(out + (size_t)gn * ND))[c4];
            acc[j][0] = o.x; acc[j][1] = o.y; acc[j][2] = o.z; acc[j][3] = o.w;
        }
    }

    const int seg_start = include_root ? -1 : 0;
    for (int seg = seg_start; seg < nseg; ++seg) {
        const float* A = (seg < 0) ? A0 : (msg + (size_t)seg * N * ND);
        const float* W = (seg < 0) ? root : (Wseg + (size_t)seg * ND * ND);

        __syncthreads();   // protect LDS reads of previous segment
        // stage A tile (64 x 128 f32), scaled by 1/max(cnt,1) for msg segments
#pragma unroll
        for (int j = 0; j < 8; ++j) {
            int row = ng + j * 8;
            int gn = n0 + row;
            float4 v = make_float4(0.f, 0.f, 0.f, 0.f);
            if (gn < N) {
                v = ((const float4*)(A + (size_t)gn * ND))[c4];
                if (seg >= 0) {
                    float c = cnt[(size_t)seg * N + gn];
                    float inv = 1.0f / fmaxf(c, 1.0f);
                    v.x *= inv; v.y *= inv; v.z *= inv; v.w *= inv;
                }
            }
            *((float4*)&lds[row * 132 + c4 * 4]) = v;
        }
        __syncthreads();

        const float4* W4 = (const float4*)W;
        for (int k = 0; k < ND; k += 4) {
            float4 w0 = W4[(k + 0) * 32 + c4];
            float4 w1 = W4[(k + 1) * 32 + c4];
            float4 w2 = W4[(k + 2) * 32 + c4];
            float4 w3 = W4[(k + 3) * 32 + c4];
#pragma unroll
            for (int j = 0; j < 8; ++j) {
                const float4 a = *(const float4*)&lds[(ng + j * 8) * 132 + k];
                acc[j][0] += a.x * w0.x + a.y * w1.x + a.z * w2.x + a.w * w3.x;
                acc[j][1] += a.x * w0.y + a.y * w1.y + a.z * w2.y + a.w * w3.y;
                acc[j][2] += a.x * w0.z + a.y * w1.z + a.z * w2.z + a.w * w3.z;
                acc[j][3] += a.x * w0.w + a.y * w1.w + a.z * w2.w + a.w * w3.w;
            }
        }
    }

    float4 b = make_float4(0.f, 0.f, 0.f, 0.f);
    if (finalize) b = ((const float4*)bias)[c4];
#pragma unroll
    for (int j = 0; j < 8; ++j) {
        int gn = n0 + ng + j * 8;
        if (gn < N) {
            float4 o;
            o.x = acc[j][0] + b.x;
            o.y = acc[j][1] + b.y;
            o.z = acc[j][2] + b.z;
            o.w = acc[j][3] + b.w;
            if (finalize) {
                o.x = fmaxf(o.x, 0.f); o.y = fmaxf(o.y, 0.f);
                o.z = fmaxf(o.z, 0.f); o.w = fmaxf(o.w, 0.f);
            }
            ((float4*)(out + (size_t)gn * ND))[c4] = o;
        }
    }
}

// ----------------------------------------------------------------- launch ---
extern "C" void kernel_launch(void* const* d_in, const int* in_sizes, int n_in,
                              void* d_out, int out_size, void* d_ws, size_t ws_size,
                              hipStream_t stream) {
    const float* x     = (const float*)d_in[0];
    const int*   eidx  = (const int*)d_in[1];
    const int*   etype = (const int*)d_in[2];
    const float* W1    = (const float*)d_in[3];
    const float* root1 = (const float*)d_in[4];
    const float* b1    = (const float*)d_in[5];
    const float* W2    = (const float*)d_in[6];
    const float* root2 = (const float*)d_in[7];
    const float* b2    = (const float*)d_in[8];
    float* out = (float*)d_out;

    const int N = in_sizes[0] / ND;
    const int E = in_sizes[2];

    const int* src = eidx;
    const int* dst = eidx + E;

    // --- workspace layout, adaptive chunk size C (power of 2 dividing 16) ---
    char* ws = (char*)d_ws;
    float* h = (float*)ws;                                     // N*D
    size_t h_bytes = (size_t)N * ND * sizeof(float);
    size_t per_rel = (size_t)N * ND * sizeof(float) + (size_t)N * sizeof(float);
    size_t avail = (ws_size > h_bytes) ? (ws_size - h_bytes) : 0;
    int cfit = (int)(avail / per_rel);
    int C = (cfit >= 4) ? 4 : (cfit >= 2) ? 2 : 1;             // cap 4: keeps msg chunk (<=102 MB) L3-resident
    float* msg = (float*)(ws + h_bytes);                       // C*N*D
    float* cnt = (float*)(ws + h_bytes + (size_t)C * N * ND * sizeof(float)); // C*N

    const int scatter_blocks = (E * 32 + 255) / 256;
    const int gemm_blocks = (N + 63) / 64;

    for (int layer = 0; layer < 2; ++layer) {
        const float* A     = (layer == 0) ? x     : h;
        const float* W     = (layer == 0) ? W1    : W2;
        const float* rootp = (layer == 0) ? root1 : root2;
        const float* biasp = (layer == 0) ? b1    : b2;
        float*       outp  = (layer == 0) ? h     : out;

        for (int r0 = 0; r0 < NR; r0 += C) {
            int c = (NR - r0 < C) ? (NR - r0) : C;
            hipMemsetAsync(msg, 0, (size_t)c * N * ND * sizeof(float), stream);
            hipMemsetAsync(cnt, 0, (size_t)c * N * sizeof(float), stream);
            scatter_kernel<<<scatter_blocks, 256, 0, stream>>>(
                A, src, dst, etype, msg, cnt, E, N, r0, r0 + c);
            gemm_kernel<<<gemm_blocks, 256, 0, stream>>>(
                A, msg, cnt, W + (size_t)r0 * ND * ND, rootp, biasp, outp,
                N, c, r0 == 0 ? 1 : 0, (r0 + c == NR) ? 1 : 0);
        }
    }
}

// Round 4
// 2349.413 us; speedup vs baseline: 3.1868x; 3.1868x over previous
//
#include <hip/hip_runtime.h>

// RGCN 2-layer forward for MI355X (gfx950). N=50000, D=128, R=16, E=1600000.
//
// Round-3 counters: 76% of time was fp32-atomicAdd scatter (8x715us, VALUBusy 3%).
// This version removes the scatter entirely:
//   1. counting-sort edges by key = rel*N+dst (hist -> 2-level scan -> fill),
//      done ONCE per call (edge list shared by both layers).
//   2. GEMM stages each (rel, node) segment by GATHERING its ~2 source rows of
//      A and summing in registers (mean = sum * cnt_inv), then contracts with
//      W_r over k. No msg buffer, no memsets of 100MB, no fp32 atomics.
//
// ws layout: h (N*D f32) | hist (M int) | seg_off (M+1 int) | cursor (M int) |
//            cnt_inv (M f32) | bsum (1024 int) | sorted_src (E int),  M = R*N.

#define ND 128
#define NR 16

// ---------------------------------------------------------------- sorting ---
__global__ __launch_bounds__(256) void hist_kernel(
    const int* __restrict__ dst, const int* __restrict__ rel,
    int* __restrict__ hist, int E, int N)
{
    int e = blockIdx.x * 256 + threadIdx.x;
    if (e >= E) return;
    atomicAdd(&hist[rel[e] * N + dst[e]], 1);
}

// Block scans 1024 elements (256 thr x 4). Writes per-element exclusive
// prefix (block-local) to seg_off, block total to bsum, and cnt_inv.
__global__ __launch_bounds__(256) void scan1_kernel(
    const int* __restrict__ hist, int* __restrict__ seg_off,
    float* __restrict__ cnt_inv, int* __restrict__ bsum, int M)
{
    __shared__ int sdata[256];
    const int t = threadIdx.x;
    const int base = blockIdx.x * 1024;
    int v[4]; int s = 0;
#pragma unroll
    for (int q = 0; q < 4; ++q) {
        int i = base + 4 * t + q;
        int hv = (i < M) ? hist[i] : 0;
        v[q] = hv; s += hv;
        if (i < M) cnt_inv[i] = 1.0f / fmaxf((float)hv, 1.0f);
    }
    sdata[t] = s;
    __syncthreads();
    for (int off = 1; off < 256; off <<= 1) {
        int tmp = (t >= off) ? sdata[t - off] : 0;
        __syncthreads();
        sdata[t] += tmp;
        __syncthreads();
    }
    int run = sdata[t] - s;  // exclusive prefix of this thread's chunk
#pragma unroll
    for (int q = 0; q < 4; ++q) {
        int i = base + 4 * t + q;
        if (i < M) seg_off[i] = run;
        run += v[q];
    }
    if (t == 255) bsum[blockIdx.x] = sdata[255];
}

// Single block: exclusive scan of up to 1024 block sums in place.
__global__ __launch_bounds__(1024) void scan2_kernel(int* __restrict__ bsum, int NB)
{
    __shared__ int sdata[1024];
    const int t = threadIdx.x;
    int v = (t < NB) ? bsum[t] : 0;
    sdata[t] = v;
    __syncthreads();
    for (int off = 1; off < 1024; off <<= 1) {
        int tmp = (t >= off) ? sdata[t - off] : 0;
        __syncthreads();
        sdata[t] += tmp;
        __syncthreads();
    }
    if (t < NB) bsum[t] = sdata[t] - v;
}

__global__ __launch_bounds__(256) void scan3_kernel(
    int* __restrict__ seg_off, int* __restrict__ cursor,
    const int* __restrict__ bsum, int M, int E)
{
    const int t = threadIdx.x;
    const int base = blockIdx.x * 1024;
    const int add = bsum[blockIdx.x];
#pragma unroll
    for (int q = 0; q < 4; ++q) {
        int i = base + 4 * t + q;
        if (i < M) {
            int vv = seg_off[i] + add;
            seg_off[i] = vv;
            cursor[i] = vv;
        }
    }
    if (blockIdx.x == 0 && t == 0) seg_off[M] = E;
}

__global__ __launch_bounds__(256) void fill_kernel(
    const int* __restrict__ src, const int* __restrict__ dst,
    const int* __restrict__ rel, int* __restrict__ cursor,
    int* __restrict__ sorted_src, int E, int N)
{
    int e = blockIdx.x * 256 + threadIdx.x;
    if (e >= E) return;
    int pos = atomicAdd(&cursor[rel[e] * N + dst[e]], 1);
    sorted_src[pos] = src[e];
}

// ------------------------------------------------------------- fused gemm ---
// out[n,:] = relu(bias + A0[n,:]@root + sum_r mean_{e in seg(r,n)} A0[src_e,:] @ W_r)
// Block: 256 threads, 64-node x 128-col tile. seg=-1 stages A0 rows directly;
// seg>=0 stages the gathered segment mean (CSR walk, ~2 edges avg).
// Thread (ng = tid>>5, c4 = tid&31): 8 rows (ng+8j), cols 4*c4..4*c4+3.
__global__ __launch_bounds__(256) void gemm_fused(
    const float* __restrict__ A0,         // N x 128
    const int* __restrict__ seg_off,      // R*N+1
    const int* __restrict__ sorted_src,   // E
    const float* __restrict__ cnt_inv,    // R*N
    const float* __restrict__ Wrel,       // R x 128 x 128
    const float* __restrict__ root,       // 128 x 128
    const float* __restrict__ bias,       // 128
    float* __restrict__ out,              // N x 128
    int N)
{
    __shared__ float lds[64 * 132];   // 64 rows, stride 132 (pad 4)
    const int tid = threadIdx.x;
    const int n0 = blockIdx.x * 64;
    const int c4 = tid & 31;
    const int ng = tid >> 5;
    const float4* x4 = (const float4*)A0;

    float acc[8][4];
#pragma unroll
    for (int j = 0; j < 8; ++j)
#pragma unroll
        for (int q = 0; q < 4; ++q) acc[j][q] = 0.f;

    for (int seg = -1; seg < NR; ++seg) {
        __syncthreads();   // protect LDS reads of previous segment
#pragma unroll
        for (int j = 0; j < 8; ++j) {
            int row = ng + j * 8;
            int gn = n0 + row;
            float4 v = make_float4(0.f, 0.f, 0.f, 0.f);
            if (gn < N) {
                if (seg < 0) {
                    v = x4[(size_t)gn * 32 + c4];
                } else {
                    int s = seg * N + gn;
                    int b0 = seg_off[s], e1 = seg_off[s + 1];
                    for (int e = b0; e < e1; ++e) {
                        int sr = sorted_src[e];
                        float4 xv = x4[(size_t)sr * 32 + c4];  // coalesced 512B/row
                        v.x += xv.x; v.y += xv.y; v.z += xv.z; v.w += xv.w;
                    }
                    float inv = cnt_inv[s];
                    v.x *= inv; v.y *= inv; v.z *= inv; v.w *= inv;
                }
            }
            *((float4*)&lds[row * 132 + c4 * 4]) = v;
        }
        __syncthreads();

        const float* W = (seg < 0) ? root : (Wrel + (size_t)seg * ND * ND);
        const float4* W4 = (const float4*)W;
        for (int k = 0; k < ND; k += 4) {
            float4 w0 = W4[(k + 0) * 32 + c4];
            float4 w1 = W4[(k + 1) * 32 + c4];
            float4 w2 = W4[(k + 2) * 32 + c4];
            float4 w3 = W4[(k + 3) * 32 + c4];
#pragma unroll
            for (int j = 0; j < 8; ++j) {
                const float4 a = *(const float4*)&lds[(ng + j * 8) * 132 + k];
                acc[j][0] += a.x * w0.x + a.y * w1.x + a.z * w2.x + a.w * w3.x;
                acc[j][1] += a.x * w0.y + a.y * w1.y + a.z * w2.y + a.w * w3.y;
                acc[j][2] += a.x * w0.z + a.y * w1.z + a.z * w2.z + a.w * w3.z;
                acc[j][3] += a.x * w0.w + a.y * w1.w + a.z * w2.w + a.w * w3.w;
            }
        }
    }

    float4 b = ((const float4*)bias)[c4];
#pragma unroll
    for (int j = 0; j < 8; ++j) {
        int gn = n0 + ng + j * 8;
        if (gn < N) {
            float4 o;
            o.x = fmaxf(acc[j][0] + b.x, 0.f);
            o.y = fmaxf(acc[j][1] + b.y, 0.f);
            o.z = fmaxf(acc[j][2] + b.z, 0.f);
            o.w = fmaxf(acc[j][3] + b.w, 0.f);
            ((float4*)(out + (size_t)gn * ND))[c4] = o;
        }
    }
}

// ----------------------------------------------------------------- launch ---
extern "C" void kernel_launch(void* const* d_in, const int* in_sizes, int n_in,
                              void* d_out, int out_size, void* d_ws, size_t ws_size,
                              hipStream_t stream) {
    const float* x     = (const float*)d_in[0];
    const int*   eidx  = (const int*)d_in[1];
    const int*   etype = (const int*)d_in[2];
    const float* W1    = (const float*)d_in[3];
    const float* root1 = (const float*)d_in[4];
    const float* b1    = (const float*)d_in[5];
    const float* W2    = (const float*)d_in[6];
    const float* root2 = (const float*)d_in[7];
    const float* b2    = (const float*)d_in[8];
    float* out = (float*)d_out;

    const int N = in_sizes[0] / ND;
    const int E = in_sizes[2];
    const int M = NR * N;                    // 800000 segment keys

    const int* src = eidx;
    const int* dst = eidx + E;

    // --- workspace carve-up (~45 MB total) ---
    char* p = (char*)d_ws;
    auto carve = [&](size_t bytes) { char* q = p; p += (bytes + 255) & ~(size_t)255; return q; };
    float* h          = (float*)carve((size_t)N * ND * sizeof(float));
    int*   hist       = (int*)  carve((size_t)M * sizeof(int));
    int*   seg_off    = (int*)  carve((size_t)(M + 1) * sizeof(int));
    int*   cursor     = (int*)  carve((size_t)M * sizeof(int));
    float* cnt_inv    = (float*)carve((size_t)M * sizeof(float));
    int*   bsum       = (int*)  carve(1024 * sizeof(int));
    int*   sorted_src = (int*)  carve((size_t)E * sizeof(int));

    const int eb = (E + 255) / 256;          // edge-grid blocks
    const int NB = (M + 1023) / 1024;        // scan blocks (782 <= 1024)
    const int gemm_blocks = (N + 63) / 64;

    // --- counting sort by (rel, dst): shared by both layers ---
    hipMemsetAsync(hist, 0, (size_t)M * sizeof(int), stream);
    hist_kernel<<<eb, 256, 0, stream>>>(dst, etype, hist, E, N);
    scan1_kernel<<<NB, 256, 0, stream>>>(hist, seg_off, cnt_inv, bsum, M);
    scan2_kernel<<<1, 1024, 0, stream>>>(bsum, NB);
    scan3_kernel<<<NB, 256, 0, stream>>>(seg_off, cursor, bsum, M, E);
    fill_kernel<<<eb, 256, 0, stream>>>(src, dst, etype, cursor, sorted_src, E, N);

    // --- layer 1: x -> h,  layer 2: h -> out ---
    gemm_fused<<<gemm_blocks, 256, 0, stream>>>(
        x, seg_off, sorted_src, cnt_inv, W1, root1, b1, h, N);
    gemm_fused<<<gemm_blocks, 256, 0, stream>>>(
        h, seg_off, sorted_src, cnt_inv, W2, root2, b2, out, N);
}

// Round 5
// 1182.316 us; speedup vs baseline: 6.3326x; 1.9871x over previous
//
#include <hip/hip_runtime.h>

// RGCN 2-layer forward for MI355X (gfx950). N=50000, D=128, R=16, E=1600000.
//
// Round-4 counters: gemm_fused = 97% of time, VALUBusy 26%, Occupancy 19.6%,
// MfmaUtil 0 -> latency-bound serial CSR walks + fp32 VALU math.
// Round-5 structure:
//   sort once:  counting sort of edges by key rel*N+dst  (unchanged)
//   per layer, per relation chunk [c0, c0+cc):
//     gather_mean: one 32-lane group per (rel,dst) segment -> bf16 msg chunk
//     gemm_mfma:   acc[n,:] += sum_r msg[r,n,:] @ W_r  via mfma 16x16x32 bf16
//                  (+ x@root on first chunk; +bias, ReLU, store on last)
//   layer-1 output stored bf16 (feeds layer-2 gather + root term).
//
// ws: h_bf | x_bf | Wt1 | Wt2 | acc | hist | seg_off | cursor | cnt_inv |
//     bsum | sorted_src | msg(C*N*128 bf16),  C adaptive (16/8/4/2/1).

#define ND 128
#define NR 16

typedef __attribute__((ext_vector_type(8))) short bf16x8;
typedef __attribute__((ext_vector_type(4))) float f32x4;

__device__ __forceinline__ unsigned short f2b(float f) {
    unsigned u = __float_as_uint(f);
    u += 0x7FFFu + ((u >> 16) & 1u);          // round-to-nearest-even
    return (unsigned short)(u >> 16);
}

// ---------------------------------------------------------------- sorting ---
__global__ __launch_bounds__(256) void hist_kernel(
    const int* __restrict__ dst, const int* __restrict__ rel,
    int* __restrict__ hist, int E, int N)
{
    int e = blockIdx.x * 256 + threadIdx.x;
    if (e >= E) return;
    atomicAdd(&hist[rel[e] * N + dst[e]], 1);
}

__global__ __launch_bounds__(256) void scan1_kernel(
    const int* __restrict__ hist, int* __restrict__ seg_off,
    float* __restrict__ cnt_inv, int* __restrict__ bsum, int M)
{
    __shared__ int sdata[256];
    const int t = threadIdx.x;
    const int base = blockIdx.x * 1024;
    int v[4]; int s = 0;
#pragma unroll
    for (int q = 0; q < 4; ++q) {
        int i = base + 4 * t + q;
        int hv = (i < M) ? hist[i] : 0;
        v[q] = hv; s += hv;
        if (i < M) cnt_inv[i] = 1.0f / fmaxf((float)hv, 1.0f);
    }
    sdata[t] = s;
    __syncthreads();
    for (int off = 1; off < 256; off <<= 1) {
        int tmp = (t >= off) ? sdata[t - off] : 0;
        __syncthreads();
        sdata[t] += tmp;
        __syncthreads();
    }
    int run = sdata[t] - s;
#pragma unroll
    for (int q = 0; q < 4; ++q) {
        int i = base + 4 * t + q;
        if (i < M) seg_off[i] = run;
        run += v[q];
    }
    if (t == 255) bsum[blockIdx.x] = sdata[255];
}

__global__ __launch_bounds__(1024) void scan2_kernel(int* __restrict__ bsum, int NB)
{
    __shared__ int sdata[1024];
    const int t = threadIdx.x;
    int v = (t < NB) ? bsum[t] : 0;
    sdata[t] = v;
    __syncthreads();
    for (int off = 1; off < 1024; off <<= 1) {
        int tmp = (t >= off) ? sdata[t - off] : 0;
        __syncthreads();
        sdata[t] += tmp;
        __syncthreads();
    }
    if (t < NB) bsum[t] = sdata[t] - v;
}

__global__ __launch_bounds__(256) void scan3_kernel(
    int* __restrict__ seg_off, int* __restrict__ cursor,
    const int* __restrict__ bsum, int M, int E)
{
    const int t = threadIdx.x;
    const int base = blockIdx.x * 1024;
    const int add = bsum[blockIdx.x];
#pragma unroll
    for (int q = 0; q < 4; ++q) {
        int i = base + 4 * t + q;
        if (i < M) {
            int vv = seg_off[i] + add;
            seg_off[i] = vv;
            cursor[i] = vv;
        }
    }
    if (blockIdx.x == 0 && t == 0) seg_off[M] = E;
}

__global__ __launch_bounds__(256) void fill_kernel(
    const int* __restrict__ src, const int* __restrict__ dst,
    const int* __restrict__ rel, int* __restrict__ cursor,
    int* __restrict__ sorted_src, int E, int N)
{
    int e = blockIdx.x * 256 + threadIdx.x;
    if (e >= E) return;
    int pos = atomicAdd(&cursor[rel[e] * N + dst[e]], 1);
    sorted_src[pos] = src[e];
}

// --------------------------------------------------------------- convert ---
__global__ __launch_bounds__(256) void conv_x_kernel(
    const float* __restrict__ x, unsigned short* __restrict__ xb, int n4)
{
    int i = blockIdx.x * 256 + threadIdx.x;
    if (i >= n4) return;
    float4 v = ((const float4*)x)[i];
    uint2 o;
    o.x = (unsigned)f2b(v.x) | ((unsigned)f2b(v.y) << 16);
    o.y = (unsigned)f2b(v.z) | ((unsigned)f2b(v.w) << 16);
    ((uint2*)xb)[i] = o;
}

// Wt[mat][n][k] = bf16( mat<16 ? W[mat][k][n] : root[k][n] ),  17 mats/layer.
__global__ __launch_bounds__(256) void conv_w_kernel(
    const float* __restrict__ W, const float* __restrict__ root,
    unsigned short* __restrict__ Wt)
{
    int t = blockIdx.x * 256 + threadIdx.x;
    if (t >= 17 * 16384) return;
    int mat = t >> 14;
    int off = t & 16383;
    int n = off >> 7;
    int k = off & 127;
    float v = (mat < 16) ? W[(size_t)mat * 16384 + k * 128 + n] : root[k * 128 + n];
    Wt[t] = f2b(v);
}

// ----------------------------------------------------------- gather mean ---
// One 32-lane group per (rel,dst) segment; lane c4 owns cols [4c4, 4c4+4).
// msg[g][col] = bf16( cnt_inv * sum_{e in seg} A[src_e][col] ),  A bf16.
__global__ __launch_bounds__(256) void gather_mean(
    const unsigned short* __restrict__ A,    // N x 128 bf16
    const int* __restrict__ seg_off,
    const int* __restrict__ sorted_src,
    const float* __restrict__ cnt_inv,
    unsigned short* __restrict__ msg,        // cc x N x 128 bf16
    int N, int r0, int ccN)
{
    int g = blockIdx.x * 8 + (threadIdx.x >> 5);
    if (g >= ccN) return;
    int c4 = threadIdx.x & 31;
    int s = r0 * N + g;
    int b0 = seg_off[s], e1 = seg_off[s + 1];
    float v0 = 0.f, v1 = 0.f, v2 = 0.f, v3 = 0.f;
    for (int e = b0; e < e1; ++e) {
        int sr = sorted_src[e];
        uint2 w = *(const uint2*)(A + (size_t)sr * ND + c4 * 4);
        v0 += __uint_as_float(w.x << 16);
        v1 += __uint_as_float(w.x & 0xFFFF0000u);
        v2 += __uint_as_float(w.y << 16);
        v3 += __uint_as_float(w.y & 0xFFFF0000u);
    }
    float inv = cnt_inv[s];
    v0 *= inv; v1 *= inv; v2 *= inv; v3 *= inv;
    uint2 o;
    o.x = (unsigned)f2b(v0) | ((unsigned)f2b(v1) << 16);
    o.y = (unsigned)f2b(v2) | ((unsigned)f2b(v3) << 16);
    *(uint2*)(msg + (size_t)g * ND + c4 * 4) = o;
}

// -------------------------------------------------------------- mfma gemm ---
// Block 256 = 4 waves; wave w: rows [blk*64 + w*16, +16) x 128 cols.
// A-frag: A[m=lane&15][k=quad*8+j] (16B load). B-frag: Wt[n=lane&15][k=quad*8+j].
// C/D: col = lane&15, row = quad*4 + reg.
__global__ __launch_bounds__(256) void gemm_mfma(
    const unsigned short* __restrict__ msg,   // cc x N x 128 bf16
    const unsigned short* __restrict__ xb,    // N x 128 bf16 (root operand)
    const unsigned short* __restrict__ Wt,    // [17][128][128] bf16 (n-major)
    const float* __restrict__ bias,
    float* __restrict__ acc_buf,              // N x 128 f32
    unsigned short* __restrict__ out_bf,      // finalize dest (layer 1) or null
    float* __restrict__ out_f32,              // finalize dest (layer 2) or null
    int N, int c0, int cc, int include_root, int load_acc, int finalize)
{
    const int lane = threadIdx.x & 63;
    const int wv = threadIdx.x >> 6;
    const int quad = lane >> 4;
    const int l16 = lane & 15;
    const int m0 = blockIdx.x * 64 + wv * 16;
    const int arow = m0 + l16;

    f32x4 acc[8];
    if (load_acc) {
#pragma unroll
        for (int ct = 0; ct < 8; ++ct)
#pragma unroll
            for (int rg = 0; rg < 4; ++rg) {
                int r = m0 + quad * 4 + rg;
                acc[ct][rg] = (r < N) ? acc_buf[(size_t)r * ND + ct * 16 + l16] : 0.f;
            }
    } else {
#pragma unroll
        for (int ct = 0; ct < 8; ++ct) {
            f32x4 z = {0.f, 0.f, 0.f, 0.f};
            acc[ct] = z;
        }
    }

    for (int rel = include_root ? -1 : 0; rel < cc; ++rel) {
        const unsigned short* A = (rel < 0) ? xb : msg + (size_t)rel * N * ND;
        const unsigned short* B = (rel < 0) ? Wt + (size_t)16 * 16384
                                            : Wt + (size_t)(c0 + rel) * 16384;
#pragma unroll
        for (int kt = 0; kt < 4; ++kt) {
            int k = kt * 32 + quad * 8;
            bf16x8 a = {0, 0, 0, 0, 0, 0, 0, 0};
            if (arow < N) a = *(const bf16x8*)(A + (size_t)arow * ND + k);
#pragma unroll
            for (int ct = 0; ct < 8; ++ct) {
                bf16x8 b = *(const bf16x8*)(B + (size_t)(ct * 16 + l16) * ND + k);
                acc[ct] = __builtin_amdgcn_mfma_f32_16x16x32_bf16(a, b, acc[ct], 0, 0, 0);
            }
        }
    }

    if (!finalize) {
#pragma unroll
        for (int ct = 0; ct < 8; ++ct)
#pragma unroll
            for (int rg = 0; rg < 4; ++rg) {
                int r = m0 + quad * 4 + rg;
                if (r < N) acc_buf[(size_t)r * ND + ct * 16 + l16] = acc[ct][rg];
            }
    } else {
#pragma unroll
        for (int ct = 0; ct < 8; ++ct) {
            float bb = bias[ct * 16 + l16];
#pragma unroll
            for (int rg = 0; rg < 4; ++rg) {
                int r = m0 + quad * 4 + rg;
                if (r < N) {
                    float v = fmaxf(acc[ct][rg] + bb, 0.f);
                    if (out_bf) out_bf[(size_t)r * ND + ct * 16 + l16] = f2b(v);
                    else        out_f32[(size_t)r * ND + ct * 16 + l16] = v;
                }
            }
        }
    }
}

// ----------------------------------------------------------------- launch ---
extern "C" void kernel_launch(void* const* d_in, const int* in_sizes, int n_in,
                              void* d_out, int out_size, void* d_ws, size_t ws_size,
                              hipStream_t stream) {
    const float* x     = (const float*)d_in[0];
    const int*   eidx  = (const int*)d_in[1];
    const int*   etype = (const int*)d_in[2];
    const float* W1    = (const float*)d_in[3];
    const float* root1 = (const float*)d_in[4];
    const float* b1    = (const float*)d_in[5];
    const float* W2    = (const float*)d_in[6];
    const float* root2 = (const float*)d_in[7];
    const float* b2    = (const float*)d_in[8];
    float* out = (float*)d_out;

    const int N = in_sizes[0] / ND;
    const int E = in_sizes[2];
    const int M = NR * N;

    const int* src = eidx;
    const int* dst = eidx + E;

    // --- workspace carve-up ---
    char* p = (char*)d_ws;
    auto carve = [&](size_t bytes) { char* q = p; p += (bytes + 255) & ~(size_t)255; return q; };
    unsigned short* h_bf  = (unsigned short*)carve((size_t)N * ND * 2);
    unsigned short* x_bf  = (unsigned short*)carve((size_t)N * ND * 2);
    unsigned short* Wt1   = (unsigned short*)carve((size_t)17 * 16384 * 2);
    unsigned short* Wt2   = (unsigned short*)carve((size_t)17 * 16384 * 2);
    float* acc            = (float*)carve((size_t)N * ND * 4);
    int*   hist           = (int*)  carve((size_t)M * 4);
    int*   seg_off        = (int*)  carve((size_t)(M + 1) * 4);
    int*   cursor         = (int*)  carve((size_t)M * 4);
    float* cnt_inv        = (float*)carve((size_t)M * 4);
    int*   bsum           = (int*)  carve(1024 * 4);
    int*   sorted_src     = (int*)  carve((size_t)E * 4);

    size_t chunk_bytes = (size_t)N * ND * 2;         // one relation of bf16 msg
    size_t used = (size_t)(p - (char*)d_ws);
    int C = 1;
    const int cand[4] = {16, 8, 4, 2};
    for (int i = 0; i < 4; ++i)
        if (used + (size_t)cand[i] * chunk_bytes + 256 <= ws_size) { C = cand[i]; break; }
    unsigned short* msg = (unsigned short*)carve((size_t)C * chunk_bytes);

    const int eb = (E + 255) / 256;
    const int NB = (M + 1023) / 1024;
    const int gemm_blocks = (N + 63) / 64;

    // --- counting sort by (rel, dst): shared by both layers ---
    hipMemsetAsync(hist, 0, (size_t)M * 4, stream);
    hist_kernel<<<eb, 256, 0, stream>>>(dst, etype, hist, E, N);
    scan1_kernel<<<NB, 256, 0, stream>>>(hist, seg_off, cnt_inv, bsum, M);
    scan2_kernel<<<1, 1024, 0, stream>>>(bsum, NB);
    scan3_kernel<<<NB, 256, 0, stream>>>(seg_off, cursor, bsum, M, E);
    fill_kernel<<<eb, 256, 0, stream>>>(src, dst, etype, cursor, sorted_src, E, N);

    // --- bf16 conversions ---
    conv_x_kernel<<<((N * ND / 4) + 255) / 256, 256, 0, stream>>>(x, x_bf, N * ND / 4);
    conv_w_kernel<<<(17 * 16384 + 255) / 256, 256, 0, stream>>>(W1, root1, Wt1);
    conv_w_kernel<<<(17 * 16384 + 255) / 256, 256, 0, stream>>>(W2, root2, Wt2);

    // --- two layers ---
    for (int layer = 0; layer < 2; ++layer) {
        const unsigned short* A  = (layer == 0) ? x_bf : h_bf;
        const unsigned short* Wt = (layer == 0) ? Wt1  : Wt2;
        const float* biasp       = (layer == 0) ? b1   : b2;

        for (int c0 = 0; c0 < NR; c0 += C) {
            int cc = (NR - c0 < C) ? (NR - c0) : C;
            int ccN = cc * N;
            gather_mean<<<(ccN + 7) / 8, 256, 0, stream>>>(
                A, seg_off, sorted_src, cnt_inv, msg, N, c0, ccN);
            int fin = (c0 + cc == NR) ? 1 : 0;
            gemm_mfma<<<gemm_blocks, 256, 0, stream>>>(
                msg, A, Wt, biasp, acc,
                (fin && layer == 0) ? h_bf : (unsigned short*)nullptr,
                (fin && layer == 1) ? out : (float*)nullptr,
                N, c0, cc, c0 == 0 ? 1 : 0, c0 > 0 ? 1 : 0, fin);
        }
    }
}

// Round 6
// 583.650 us; speedup vs baseline: 12.8281x; 2.0257x over previous
//
#include <hip/hip_runtime.h>

// RGCN 2-layer forward for MI355X (gfx950). N=50000, D=128, R=16, E=1600000.
//
// Round-5 counters: gemm_mfma ~150us each (4/call at C=8), MfmaUtil 3.8%,
// B-operand re-read from L2 per wave (~1.7 GB/layer) -> latency/L2 bound.
// Round-6: weights pre-swizzled into MFMA fragment order; each 128-row block
// stages one relation's 32 KB B into LDS (linear copy, bank-even) and all 8
// waves consume via ds_read_b128. Gather: 16-lane groups + 2-way edge unroll.
//
// ws: h_bf | x_bf | Wt1 | Wt2 | acc | hist | seg_off | cursor | cnt_inv |
//     bsum | sorted_src | msg(C*N*128 bf16),  C adaptive (16/8/4/2).

#define ND 128
#define NR 16

typedef __attribute__((ext_vector_type(8))) short bf16x8;
typedef __attribute__((ext_vector_type(4))) float f32x4;

__device__ __forceinline__ unsigned short f2b(float f) {
    unsigned u = __float_as_uint(f);
    u += 0x7FFFu + ((u >> 16) & 1u);          // round-to-nearest-even
    return (unsigned short)(u >> 16);
}

// ---------------------------------------------------------------- sorting ---
__global__ __launch_bounds__(256) void hist_kernel(
    const int* __restrict__ dst, const int* __restrict__ rel,
    int* __restrict__ hist, int E, int N)
{
    int e = blockIdx.x * 256 + threadIdx.x;
    if (e >= E) return;
    atomicAdd(&hist[rel[e] * N + dst[e]], 1);
}

__global__ __launch_bounds__(256) void scan1_kernel(
    const int* __restrict__ hist, int* __restrict__ seg_off,
    float* __restrict__ cnt_inv, int* __restrict__ bsum, int M)
{
    __shared__ int sdata[256];
    const int t = threadIdx.x;
    const int base = blockIdx.x * 1024;
    int v[4]; int s = 0;
#pragma unroll
    for (int q = 0; q < 4; ++q) {
        int i = base + 4 * t + q;
        int hv = (i < M) ? hist[i] : 0;
        v[q] = hv; s += hv;
        if (i < M) cnt_inv[i] = 1.0f / fmaxf((float)hv, 1.0f);
    }
    sdata[t] = s;
    __syncthreads();
    for (int off = 1; off < 256; off <<= 1) {
        int tmp = (t >= off) ? sdata[t - off] : 0;
        __syncthreads();
        sdata[t] += tmp;
        __syncthreads();
    }
    int run = sdata[t] - s;
#pragma unroll
    for (int q = 0; q < 4; ++q) {
        int i = base + 4 * t + q;
        if (i < M) seg_off[i] = run;
        run += v[q];
    }
    if (t == 255) bsum[blockIdx.x] = sdata[255];
}

__global__ __launch_bounds__(1024) void scan2_kernel(int* __restrict__ bsum, int NB)
{
    __shared__ int sdata[1024];
    const int t = threadIdx.x;
    int v = (t < NB) ? bsum[t] : 0;
    sdata[t] = v;
    __syncthreads();
    for (int off = 1; off < 1024; off <<= 1) {
        int tmp = (t >= off) ? sdata[t - off] : 0;
        __syncthreads();
        sdata[t] += tmp;
        __syncthreads();
    }
    if (t < NB) bsum[t] = sdata[t] - v;
}

__global__ __launch_bounds__(256) void scan3_kernel(
    int* __restrict__ seg_off, int* __restrict__ cursor,
    const int* __restrict__ bsum, int M, int E)
{
    const int t = threadIdx.x;
    const int base = blockIdx.x * 1024;
    const int add = bsum[blockIdx.x];
#pragma unroll
    for (int q = 0; q < 4; ++q) {
        int i = base + 4 * t + q;
        if (i < M) {
            int vv = seg_off[i] + add;
            seg_off[i] = vv;
            cursor[i] = vv;
        }
    }
    if (blockIdx.x == 0 && t == 0) seg_off[M] = E;
}

__global__ __launch_bounds__(256) void fill_kernel(
    const int* __restrict__ src, const int* __restrict__ dst,
    const int* __restrict__ rel, int* __restrict__ cursor,
    int* __restrict__ sorted_src, int E, int N)
{
    int e = blockIdx.x * 256 + threadIdx.x;
    if (e >= E) return;
    int pos = atomicAdd(&cursor[rel[e] * N + dst[e]], 1);
    sorted_src[pos] = src[e];
}

// --------------------------------------------------------------- convert ---
__global__ __launch_bounds__(256) void conv_x_kernel(
    const float* __restrict__ x, unsigned short* __restrict__ xb, int n4)
{
    int i = blockIdx.x * 256 + threadIdx.x;
    if (i >= n4) return;
    float4 v = ((const float4*)x)[i];
    uint2 o;
    o.x = (unsigned)f2b(v.x) | ((unsigned)f2b(v.y) << 16);
    o.y = (unsigned)f2b(v.z) | ((unsigned)f2b(v.w) << 16);
    ((uint2*)xb)[i] = o;
}

// Weights in MFMA-fragment order: Wt_sw[mat][(kt*8+ct)*64+lane][8 shorts],
// frag(lane) = { n = ct*16 + (lane&15), k = kt*32 + (lane>>4)*8 .. +8 }.
// mat 0..15 = W[mat] (k-major input: W[k][n]); mat 16 = root.
__global__ __launch_bounds__(256) void conv_w_kernel(
    const float* __restrict__ W, const float* __restrict__ root,
    unsigned short* __restrict__ Wt)
{
    int t = blockIdx.x * 256 + threadIdx.x;   // one thread per 16B fragment
    if (t >= 17 * 2048) return;
    int mat = t >> 11;
    int f = t & 2047;
    int lane = f & 63;
    int ctkt = f >> 6;            // kt*8 + ct
    int kt = ctkt >> 3;
    int ct = ctkt & 7;
    int n = ct * 16 + (lane & 15);
    int k = kt * 32 + (lane >> 4) * 8;
    const float* src = (mat < 16) ? (W + (size_t)mat * 16384) : root;
    uint4 o;
    o.x = (unsigned)f2b(src[(size_t)(k + 0) * ND + n]) | ((unsigned)f2b(src[(size_t)(k + 1) * ND + n]) << 16);
    o.y = (unsigned)f2b(src[(size_t)(k + 2) * ND + n]) | ((unsigned)f2b(src[(size_t)(k + 3) * ND + n]) << 16);
    o.z = (unsigned)f2b(src[(size_t)(k + 4) * ND + n]) | ((unsigned)f2b(src[(size_t)(k + 5) * ND + n]) << 16);
    o.w = (unsigned)f2b(src[(size_t)(k + 6) * ND + n]) | ((unsigned)f2b(src[(size_t)(k + 7) * ND + n]) << 16);
    *(uint4*)(Wt + (size_t)t * 8) = o;
}

// ----------------------------------------------------------- gather mean ---
// 16-lane group per (rel,dst) segment (4 independent segments per wave for
// MLP); lane owns 16B (8 cols). 2-way edge unroll overlaps src + row loads.
__global__ __launch_bounds__(256) void gather_mean(
    const unsigned short* __restrict__ A,    // N x 128 bf16
    const int* __restrict__ seg_off,
    const int* __restrict__ sorted_src,
    const float* __restrict__ cnt_inv,
    unsigned short* __restrict__ msg,        // cc x N x 128 bf16
    int N, int r0, int ccN)
{
    int g = blockIdx.x * 16 + (threadIdx.x >> 4);
    if (g >= ccN) return;
    int l = threadIdx.x & 15;
    int s = r0 * N + g;
    int b0 = seg_off[s], e1 = seg_off[s + 1];
    float a0 = 0.f, a1 = 0.f, a2 = 0.f, a3 = 0.f, a4 = 0.f, a5 = 0.f, a6 = 0.f, a7 = 0.f;
    int e = b0;
    for (; e + 2 <= e1; e += 2) {
        int s0 = sorted_src[e];
        int s1 = sorted_src[e + 1];
        uint4 u0 = *(const uint4*)(A + (size_t)s0 * ND + l * 8);
        uint4 u1 = *(const uint4*)(A + (size_t)s1 * ND + l * 8);
        a0 += __uint_as_float(u0.x << 16); a1 += __uint_as_float(u0.x & 0xFFFF0000u);
        a2 += __uint_as_float(u0.y << 16); a3 += __uint_as_float(u0.y & 0xFFFF0000u);
        a4 += __uint_as_float(u0.z << 16); a5 += __uint_as_float(u0.z & 0xFFFF0000u);
        a6 += __uint_as_float(u0.w << 16); a7 += __uint_as_float(u0.w & 0xFFFF0000u);
        a0 += __uint_as_float(u1.x << 16); a1 += __uint_as_float(u1.x & 0xFFFF0000u);
        a2 += __uint_as_float(u1.y << 16); a3 += __uint_as_float(u1.y & 0xFFFF0000u);
        a4 += __uint_as_float(u1.z << 16); a5 += __uint_as_float(u1.z & 0xFFFF0000u);
        a6 += __uint_as_float(u1.w << 16); a7 += __uint_as_float(u1.w & 0xFFFF0000u);
    }
    if (e < e1) {
        int s0 = sorted_src[e];
        uint4 u0 = *(const uint4*)(A + (size_t)s0 * ND + l * 8);
        a0 += __uint_as_float(u0.x << 16); a1 += __uint_as_float(u0.x & 0xFFFF0000u);
        a2 += __uint_as_float(u0.y << 16); a3 += __uint_as_float(u0.y & 0xFFFF0000u);
        a4 += __uint_as_float(u0.z << 16); a5 += __uint_as_float(u0.z & 0xFFFF0000u);
        a6 += __uint_as_float(u0.w << 16); a7 += __uint_as_float(u0.w & 0xFFFF0000u);
    }
    float inv = cnt_inv[s];
    uint4 o;
    o.x = (unsigned)f2b(a0 * inv) | ((unsigned)f2b(a1 * inv) << 16);
    o.y = (unsigned)f2b(a2 * inv) | ((unsigned)f2b(a3 * inv) << 16);
    o.z = (unsigned)f2b(a4 * inv) | ((unsigned)f2b(a5 * inv) << 16);
    o.w = (unsigned)f2b(a6 * inv) | ((unsigned)f2b(a7 * inv) << 16);
    *(uint4*)(msg + (size_t)g * ND + l * 8) = o;
}

// -------------------------------------------------------------- mfma gemm ---
// 512 threads = 8 waves; block covers 128 rows (wave wv: rows blk*128+wv*16).
// Per relation: stage 32 KB swizzled B into LDS (linear copy), then each wave
// reads b-frags via ds_read_b128 at lane*16B (bank-even) and MFMAs.
// A-frag: A[m=lane&15][k=quad*8+j]. C/D: col=lane&15, row=quad*4+reg.
__global__ __launch_bounds__(512, 4) void gemm_mfma(
    const unsigned short* __restrict__ msg,   // cc x N x 128 bf16
    const unsigned short* __restrict__ xb,    // N x 128 bf16 (root operand)
    const unsigned short* __restrict__ Wt,    // [17][2048][8] swizzled bf16
    const float* __restrict__ bias,
    float* __restrict__ acc_buf,              // N x 128 f32
    unsigned short* __restrict__ out_bf,      // finalize dest (layer 1) or null
    float* __restrict__ out_f32,              // finalize dest (layer 2) or null
    int N, int c0, int cc, int include_root, int load_acc, int finalize)
{
    __shared__ __align__(16) unsigned short Bs[2048 * 8];   // 32 KB
    const int tid = threadIdx.x;
    const int lane = tid & 63;
    const int wv = tid >> 6;
    const int quad = lane >> 4;
    const int l16 = lane & 15;
    const int m0 = blockIdx.x * 128 + wv * 16;
    const int arow = m0 + l16;

    f32x4 acc[8];
    if (load_acc) {
#pragma unroll
        for (int ct = 0; ct < 8; ++ct)
#pragma unroll
            for (int rg = 0; rg < 4; ++rg) {
                int r = m0 + quad * 4 + rg;
                acc[ct][rg] = (r < N) ? acc_buf[(size_t)r * ND + ct * 16 + l16] : 0.f;
            }
    } else {
#pragma unroll
        for (int ct = 0; ct < 8; ++ct) {
            f32x4 z = {0.f, 0.f, 0.f, 0.f};
            acc[ct] = z;
        }
    }

    for (int rel = include_root ? -1 : 0; rel < cc; ++rel) {
        const unsigned short* A = (rel < 0) ? xb : msg + (size_t)rel * N * ND;
        const int mat = (rel < 0) ? 16 : (c0 + rel);
        const uint4* Bsrc = (const uint4*)(Wt + (size_t)mat * 2048 * 8);

        __syncthreads();   // previous relation's LDS reads complete
#pragma unroll
        for (int i = 0; i < 4; ++i)
            ((uint4*)Bs)[tid + i * 512] = Bsrc[tid + i * 512];
        __syncthreads();

#pragma unroll
        for (int kt = 0; kt < 4; ++kt) {
            int k = kt * 32 + quad * 8;
            bf16x8 a = {0, 0, 0, 0, 0, 0, 0, 0};
            if (arow < N) a = *(const bf16x8*)(A + (size_t)arow * ND + k);
#pragma unroll
            for (int ct = 0; ct < 8; ++ct) {
                bf16x8 b = *(const bf16x8*)(Bs + (size_t)((kt * 8 + ct) * 64 + lane) * 8);
                acc[ct] = __builtin_amdgcn_mfma_f32_16x16x32_bf16(a, b, acc[ct], 0, 0, 0);
            }
        }
    }

    if (!finalize) {
#pragma unroll
        for (int ct = 0; ct < 8; ++ct)
#pragma unroll
            for (int rg = 0; rg < 4; ++rg) {
                int r = m0 + quad * 4 + rg;
                if (r < N) acc_buf[(size_t)r * ND + ct * 16 + l16] = acc[ct][rg];
            }
    } else {
#pragma unroll
        for (int ct = 0; ct < 8; ++ct) {
            float bb = bias[ct * 16 + l16];
#pragma unroll
            for (int rg = 0; rg < 4; ++rg) {
                int r = m0 + quad * 4 + rg;
                if (r < N) {
                    float v = fmaxf(acc[ct][rg] + bb, 0.f);
                    if (out_bf) out_bf[(size_t)r * ND + ct * 16 + l16] = f2b(v);
                    else        out_f32[(size_t)r * ND + ct * 16 + l16] = v;
                }
            }
        }
    }
}

// ----------------------------------------------------------------- launch ---
extern "C" void kernel_launch(void* const* d_in, const int* in_sizes, int n_in,
                              void* d_out, int out_size, void* d_ws, size_t ws_size,
                              hipStream_t stream) {
    const float* x     = (const float*)d_in[0];
    const int*   eidx  = (const int*)d_in[1];
    const int*   etype = (const int*)d_in[2];
    const float* W1    = (const float*)d_in[3];
    const float* root1 = (const float*)d_in[4];
    const float* b1    = (const float*)d_in[5];
    const float* W2    = (const float*)d_in[6];
    const float* root2 = (const float*)d_in[7];
    const float* b2    = (const float*)d_in[8];
    float* out = (float*)d_out;

    const int N = in_sizes[0] / ND;
    const int E = in_sizes[2];
    const int M = NR * N;

    const int* src = eidx;
    const int* dst = eidx + E;

    // --- workspace carve-up ---
    char* p = (char*)d_ws;
    auto carve = [&](size_t bytes) { char* q = p; p += (bytes + 255) & ~(size_t)255; return q; };
    unsigned short* h_bf  = (unsigned short*)carve((size_t)N * ND * 2);
    unsigned short* x_bf  = (unsigned short*)carve((size_t)N * ND * 2);
    unsigned short* Wt1   = (unsigned short*)carve((size_t)17 * 2048 * 8 * 2);
    unsigned short* Wt2   = (unsigned short*)carve((size_t)17 * 2048 * 8 * 2);
    float* acc            = (float*)carve((size_t)N * ND * 4);
    int*   hist           = (int*)  carve((size_t)M * 4);
    int*   seg_off        = (int*)  carve((size_t)(M + 1) * 4);
    int*   cursor         = (int*)  carve((size_t)M * 4);
    float* cnt_inv        = (float*)carve((size_t)M * 4);
    int*   bsum           = (int*)  carve(1024 * 4);
    int*   sorted_src     = (int*)  carve((size_t)E * 4);

    size_t chunk_bytes = (size_t)N * ND * 2;         // one relation of bf16 msg
    size_t used = (size_t)(p - (char*)d_ws);
    int C = 1;
    const int cand[4] = {16, 8, 4, 2};
    for (int i = 0; i < 4; ++i)
        if (used + (size_t)cand[i] * chunk_bytes + 256 <= ws_size) { C = cand[i]; break; }
    unsigned short* msg = (unsigned short*)carve((size_t)C * chunk_bytes);

    const int eb = (E + 255) / 256;
    const int NB = (M + 1023) / 1024;
    const int gemm_blocks = (N + 127) / 128;

    // --- counting sort by (rel, dst): shared by both layers ---
    hipMemsetAsync(hist, 0, (size_t)M * 4, stream);
    hist_kernel<<<eb, 256, 0, stream>>>(dst, etype, hist, E, N);
    scan1_kernel<<<NB, 256, 0, stream>>>(hist, seg_off, cnt_inv, bsum, M);
    scan2_kernel<<<1, 1024, 0, stream>>>(bsum, NB);
    scan3_kernel<<<NB, 256, 0, stream>>>(seg_off, cursor, bsum, M, E);
    fill_kernel<<<eb, 256, 0, stream>>>(src, dst, etype, cursor, sorted_src, E, N);

    // --- bf16 conversions ---
    conv_x_kernel<<<((N * ND / 4) + 255) / 256, 256, 0, stream>>>(x, x_bf, N * ND / 4);
    conv_w_kernel<<<(17 * 2048 + 255) / 256, 256, 0, stream>>>(W1, root1, Wt1);
    conv_w_kernel<<<(17 * 2048 + 255) / 256, 256, 0, stream>>>(W2, root2, Wt2);

    // --- two layers ---
    for (int layer = 0; layer < 2; ++layer) {
        const unsigned short* A  = (layer == 0) ? x_bf : h_bf;
        const unsigned short* Wt = (layer == 0) ? Wt1  : Wt2;
        const float* biasp       = (layer == 0) ? b1   : b2;

        for (int c0 = 0; c0 < NR; c0 += C) {
            int cc = (NR - c0 < C) ? (NR - c0) : C;
            int ccN = cc * N;
            gather_mean<<<(ccN + 15) / 16, 256, 0, stream>>>(
                A, seg_off, sorted_src, cnt_inv, msg, N, c0, ccN);
            int fin = (c0 + cc == NR) ? 1 : 0;
            gemm_mfma<<<gemm_blocks, 512, 0, stream>>>(
                msg, A, Wt, biasp, acc,
                (fin && layer == 0) ? h_bf : (unsigned short*)nullptr,
                (fin && layer == 1) ? out : (float*)nullptr,
                N, c0, cc, c0 == 0 ? 1 : 0, c0 > 0 ? 1 : 0, fin);
        }
    }
}